// Round 1
// baseline (1322.651 us; speedup 1.0000x reference)
//
#include <hip/hip_runtime.h>
#include <hip/hip_bf16.h>

// Problem shapes (fixed by the reference setup_inputs):
//   pred:         [16, 512, 32000] f32
//   action_probs: [16, 512] f32
//   value:        [16, 512] f32
//   critic_value: [16, 512] f32
//   segments:     [16, 512] i32 (0/1 markers)
// Output: single f32 scalar.
//
// out = policy_loss + 0.5*value_loss + 0.005*entropy_loss
//     = (-P + 0.5*A2 + 0.005*S) / (B*L)
// where S  = sum over all [B,L,V] of p*log(p)
//       P  = sum over [B,L] of advantage * segment_logprob
//       A2 = sum over [B,L] of advantage^2

#define B_DIM 16
#define L_DIM 512
#define V_DIM 32000

// ---------------------------------------------------------------------------
// Kernel A: S = sum p*log(p) over 262.1M floats (1.049 GB) — memory-bound.
// float4 loads, per-thread double accumulator, wave shuffle reduce, LDS
// combine, one f64 atomic per block.
// ---------------------------------------------------------------------------
__global__ __launch_bounds__(256) void entropy_sum_kernel(
    const float4* __restrict__ pred4, long long n4, double* __restrict__ ws) {
    long long idx    = (long long)blockIdx.x * blockDim.x + threadIdx.x;
    long long stride = (long long)gridDim.x * blockDim.x;

    double acc = 0.0;
    for (long long i = idx; i < n4; i += stride) {
        float4 p = pred4[i];
        // p in (1e-6, 1): log is finite, __logf (v_log_f32) is plenty accurate
        float s = p.x * __logf(p.x) + p.y * __logf(p.y) +
                  p.z * __logf(p.z) + p.w * __logf(p.w);
        acc += (double)s;
    }

    // wave(64) butterfly reduce on double
    for (int off = 32; off > 0; off >>= 1)
        acc += __shfl_down(acc, off, 64);

    __shared__ double s_wave[4];  // 256 threads / 64 = 4 waves
    int lane = threadIdx.x & 63;
    int wave = threadIdx.x >> 6;
    if (lane == 0) s_wave[wave] = acc;
    __syncthreads();
    if (threadIdx.x == 0) {
        double blk = s_wave[0] + s_wave[1] + s_wave[2] + s_wave[3];
        atomicAdd(ws, blk);  // global f64 atomic, ~2048 total — negligible
    }
}

// ---------------------------------------------------------------------------
// Kernel B: the [B,L] segment/policy/value part + final combine.
// One block; threads 0..15 each own one batch row (serial over L=512).
// Segment = run of positions ending at a marker (marker inclusive); every
// position in the run gets the run's logp sum, so the policy dot-product for
// the run is run_logp * run_advsum. Tail after last marker: same, except the
// LAST batch row's tail is forced to 0 (faithful to reference).
// ---------------------------------------------------------------------------
__global__ __launch_bounds__(64) void small_and_combine_kernel(
    const float* __restrict__ action_probs,
    const float* __restrict__ value,
    const float* __restrict__ critic_value,
    const int*   __restrict__ segments,
    const double* __restrict__ ws,
    float* __restrict__ out) {
    __shared__ double s_pol[B_DIM];
    __shared__ double s_adv2[B_DIM];

    int b = threadIdx.x;
    if (b < B_DIM) {
        const float* ap = action_probs + (long long)b * L_DIM;
        const float* va = value        + (long long)b * L_DIM;
        const float* cv = critic_value + (long long)b * L_DIM;
        const int*   sg = segments     + (long long)b * L_DIM;

        double pol = 0.0, adv2 = 0.0;
        float run_logp = 0.0f;
        float run_adv  = 0.0f;
        for (int l = 0; l < L_DIM; ++l) {
            float lp  = __logf(ap[l]);
            float adv = va[l] - cv[l];
            run_logp += lp;
            run_adv  += adv;
            adv2     += (double)adv * (double)adv;
            if (sg[l] != 0) {
                pol += (double)run_logp * (double)run_adv;
                run_logp = 0.0f;
                run_adv  = 0.0f;
            }
        }
        // trailing tail (after last marker): counted for all rows except the
        // last one, whose tail segment_prob stays 0 in the reference.
        if (b != B_DIM - 1)
            pol += (double)run_logp * (double)run_adv;

        s_pol[b]  = pol;
        s_adv2[b] = adv2;
    }
    __syncthreads();

    if (threadIdx.x == 0) {
        double P = 0.0, A2 = 0.0;
        for (int i = 0; i < B_DIM; ++i) { P += s_pol[i]; A2 += s_adv2[i]; }
        double S = ws[0];  // entropy sum from kernel A (stream-ordered)
        double res = (-P + 0.5 * A2 + 0.005 * S) / (double)(B_DIM * L_DIM);
        out[0] = (float)res;
    }
}

extern "C" void kernel_launch(void* const* d_in, const int* in_sizes, int n_in,
                              void* d_out, int out_size, void* d_ws, size_t ws_size,
                              hipStream_t stream) {
    const float* pred         = (const float*)d_in[0];
    const float* action_probs = (const float*)d_in[1];
    const float* value        = (const float*)d_in[2];
    const float* critic_value = (const float*)d_in[3];
    const int*   segments     = (const int*)d_in[4];
    float* out = (float*)d_out;
    double* ws = (double*)d_ws;

    // ws is poisoned to 0xAA before every timed launch — zero the accumulator.
    hipMemsetAsync(ws, 0, sizeof(double), stream);

    long long n4 = (long long)B_DIM * L_DIM * V_DIM / 4;  // 65,536,000 float4s
    entropy_sum_kernel<<<2048, 256, 0, stream>>>((const float4*)pred, n4, ws);
    small_and_combine_kernel<<<1, 64, 0, stream>>>(action_probs, value,
                                                   critic_value, segments,
                                                   ws, out);
}

// Round 2
// 1282.319 us; speedup vs baseline: 1.0315x; 1.0315x over previous
//
#include <hip/hip_runtime.h>
#include <hip/hip_bf16.h>

// Shapes (fixed): pred [16,512,32000] f32; action_probs/value/critic_value
// [16,512] f32; segments [16,512] i32. Output: 1 f32 scalar.
//
// out = (-P + 0.5*A2 + 0.005*S) / 8192
//   S  = sum_{B,L,V} p*log(p)                      (1.049 GB read — the cost)
//   P  = sum over segment runs of (sum logp)*(sum adv); tail-after-last-marker
//        counted for rows 0..14, zeroed for row 15 (faithful to reference)
//   A2 = sum (value-critic)^2

#define B_DIM 16
#define L_DIM 512
#define V_DIM 32000
#define NBLK  2048   // entropy kernel grid; also # of partial slots in ws
#define TPB   256

typedef float vfloat4 __attribute__((ext_vector_type(4)));

// ---------------------------------------------------------------------------
// Kernel A: per-block partial sums of p*log(p) into ws[blockIdx.x].
// 2048 blocks x 256 thr = 524288 threads; 65,536,000 float4s -> exactly 125
// iterations/thread. Nontemporal streaming loads (input >> L3).
// ---------------------------------------------------------------------------
__global__ __launch_bounds__(TPB) void entropy_sum_kernel(
    const vfloat4* __restrict__ pred4, double* __restrict__ partials) {
    long long idx    = (long long)blockIdx.x * TPB + threadIdx.x;
    const long long stride = (long long)NBLK * TPB;
    const long long n4 = (long long)B_DIM * L_DIM * V_DIM / 4;

    double acc = 0.0;
    for (long long i = idx; i < n4; i += stride) {
        vfloat4 p = __builtin_nontemporal_load(&pred4[i]);
        float s = p.x * __logf(p.x) + p.y * __logf(p.y) +
                  p.z * __logf(p.z) + p.w * __logf(p.w);
        acc += (double)s;
    }

    for (int off = 32; off > 0; off >>= 1)
        acc += __shfl_down(acc, off, 64);

    __shared__ double s_wave[TPB / 64];
    if ((threadIdx.x & 63) == 0) s_wave[threadIdx.x >> 6] = acc;
    __syncthreads();
    if (threadIdx.x == 0)
        partials[blockIdx.x] = s_wave[0] + s_wave[1] + s_wave[2] + s_wave[3];
}

// ---------------------------------------------------------------------------
// Kernel B: reduce entropy partials + the [B,L] segment/policy/value part +
// final combine. One block, 512 threads. Rows staged into LDS coalesced
// (2 phases x 8 rows), then 8 lanes walk their row serially over LDS.
// ---------------------------------------------------------------------------
__global__ __launch_bounds__(512) void finish_kernel(
    const float* __restrict__ action_probs,
    const float* __restrict__ value,
    const float* __restrict__ critic_value,
    const int*   __restrict__ segments,
    const double* __restrict__ partials,
    float* __restrict__ out) {
    __shared__ float         lpL[8][L_DIM];
    __shared__ float         adL[8][L_DIM];
    __shared__ unsigned char sgL[8][L_DIM];
    __shared__ double rowPol[B_DIM];
    __shared__ double rowA2[B_DIM];
    __shared__ double sred[512 / 64];

    // --- entropy partial reduction: 2048 doubles, 4 per thread ---
    double s = 0.0;
    for (int k = 0; k < NBLK / 512; ++k)
        s += partials[threadIdx.x + 512 * k];
    for (int off = 32; off > 0; off >>= 1)
        s += __shfl_down(s, off, 64);
    if ((threadIdx.x & 63) == 0) sred[threadIdx.x >> 6] = s;
    // visibility guaranteed by the __syncthreads() inside the phase loop

    // --- segment/policy/value over 16 rows, 8 per phase ---
    for (int phase = 0; phase < 2; ++phase) {
        const int rbase = phase * 8;
        // stage 8 rows (4096 positions) coalesced: 8 per thread
        for (int k = 0; k < 8; ++k) {
            int idx = threadIdx.x + 512 * k;        // 0..4095
            int r = idx >> 9, l = idx & 511;
            long long g = (long long)(rbase + r) * L_DIM + l;
            lpL[r][l] = __logf(action_probs[g]);
            adL[r][l] = value[g] - critic_value[g];
            sgL[r][l] = (unsigned char)(segments[g] != 0);
        }
        __syncthreads();
        if (threadIdx.x < 8) {
            int r = threadIdx.x;
            int row = rbase + r;
            double pol = 0.0, a2 = 0.0;
            float run_lp = 0.0f, run_ad = 0.0f;
            for (int l = 0; l < L_DIM; ++l) {
                float lp  = lpL[r][l];
                float adv = adL[r][l];
                run_lp += lp;
                run_ad += adv;
                a2 += (double)adv * (double)adv;
                if (sgL[r][l]) {
                    pol += (double)run_lp * (double)run_ad;
                    run_lp = 0.0f;
                    run_ad = 0.0f;
                }
            }
            // tail after last marker counts for all rows except the last
            if (row != B_DIM - 1)
                pol += (double)run_lp * (double)run_ad;
            rowPol[row] = pol;
            rowA2[row]  = a2;
        }
        __syncthreads();
    }

    if (threadIdx.x == 0) {
        double P = 0.0, A2 = 0.0;
        for (int i = 0; i < B_DIM; ++i) { P += rowPol[i]; A2 += rowA2[i]; }
        double S = 0.0;
        for (int i = 0; i < 512 / 64; ++i) S += sred[i];
        double res = (-P + 0.5 * A2 + 0.005 * S) / (double)(B_DIM * L_DIM);
        out[0] = (float)res;
    }
}

extern "C" void kernel_launch(void* const* d_in, const int* in_sizes, int n_in,
                              void* d_out, int out_size, void* d_ws, size_t ws_size,
                              hipStream_t stream) {
    const float* pred         = (const float*)d_in[0];
    const float* action_probs = (const float*)d_in[1];
    const float* value        = (const float*)d_in[2];
    const float* critic_value = (const float*)d_in[3];
    const int*   segments     = (const int*)d_in[4];
    float* out = (float*)d_out;
    double* partials = (double*)d_ws;   // ws[0..2047]; every slot written by
                                        // kernel A each call (0xAA-poison safe)

    entropy_sum_kernel<<<NBLK, TPB, 0, stream>>>((const vfloat4*)pred, partials);
    finish_kernel<<<1, 512, 0, stream>>>(action_probs, value, critic_value,
                                         segments, partials, out);
}